// Round 7
// baseline (2339.110 us; speedup 1.0000x reference)
//
#include <hip/hip_runtime.h>
#include <math.h>

#define L    2048
#define NCOL 4096
#define NG   1024
#define N3   3072
#define T    512
#define NW   8            // waves per block
#define EPT  8            // NCOL / T
#define NB   2048         // buckets (exact: floor(x*2048), power-of-two mult)
#define FEPS 1.1920929e-07f

typedef unsigned long long u64;
typedef unsigned short u16;
typedef unsigned int u32;

__device__ __forceinline__ int lower_bound_f(const float* a, int lo, int hi, float v) {
  // exact replica of numpy's npy_binsearch (side='left') on [lo,hi)
  while (lo < hi) {
    int mid = (lo + hi) >> 1;
    if (a[mid] < v) lo = mid + 1; else hi = mid;
  }
  return lo;
}

__device__ __forceinline__ int bucket_of_bits(unsigned xb) {
  float f = __uint_as_float(xb);
  int b = (int)(f * (float)NB);          // exact: mult by 2^11
  return b > NB - 1 ? NB - 1 : b;
}

// Exact grid 'rest' value, IDENTICAL fp expression to the reference path:
// xnew = -1 + 3j/3071 (fp32, exact mul, rounded div), rest = xnew - floor.
// On branch b (floor == b-1 for the j-ranges used) rest = xnew - (b-1).
__device__ __forceinline__ float rest_at(int j, float ixbf) {
  float xn = -1.0f + (3.0f * (float)j) / 3071.0f;
  return xn - ixbf;
}

// F(v): first j in [js, je] with rest_j > v (je = "none"). rest_j is strictly
// increasing in j within a branch (step ~9.8e-4 >> ulp), so estimate + exact
// fix-up terminates in ~1-2 iterations. All decisions use rest_at == the
// reference's own expression -> assignment matches searchsorted bit-exactly.
__device__ __forceinline__ int F_edge(float v, int js, int je, float ixbf, float bf) {
  int jj = (int)((v + bf) * (3071.0f / 3.0f));
  jj = jj < js ? js : (jj > je ? je : jj);
  while (jj > js && rest_at(jj - 1, ixbf) > v) --jj;
  while (jj < je && rest_at(jj, ixbf) <= v) ++jj;
  return jj;
}

// LDS layout (37,392 B dynamic -> 4 blocks/CU, 32 waves/CU):
//   [0,32768)      pairs u64[4096] (scatter+sort); DEAD after the register
//                  read-back -> ecdf f32[3072] overlays [0,12288).
//   [32768,36872)  cnt u16[2050] (packed u32 words for atomics), padded
//   [36872,37392)  lut2 u16[257]
__global__ __launch_bounds__(T, 8) void lcot_rows(const float* __restrict__ X,
                                                  const float* __restrict__ W,
                                                  float* __restrict__ rowsum) {
  extern __shared__ char smem[];
  u64*   pairs = (u64*)smem;
  float* ecdf  = (float*)smem;                    // overlay after pairs dies
  u16*   cnt16 = (u16*)(smem + 32768);
  u32*   cntw  = (u32*)(smem + 32768);
  u16*   lut2  = (u16*)(smem + 36872);

  __shared__ float redA[NW], redB[NW], fwt[NW];
  __shared__ float xw8[NW], yw8[NW];
  __shared__ int   iwt[NW];
  __shared__ float s_alpha;

  const int tid  = threadIdx.x;
  const int lane = tid & 63;
  const int wave = tid >> 6;
  const int row  = blockIdx.x;
  const float* xr = X + (size_t)row * NCOL;
  const float* wr = W + (size_t)row * NCOL;

  // ---- zero packed histogram (1025 u32 words incl. sentinel word) ----
  for (int i = tid; i < 1025; i += T) cntw[i] = 0u;

  // ---- load 8 consecutive elems, pack stable keys, alpha partials ----
  u64 key[EPT];
  float sxw = 0.f, sw = 0.f;
  const float4* xr4 = (const float4*)xr;
  const float4* wr4 = (const float4*)wr;
#pragma unroll
  for (int c = 0; c < 2; ++c) {
    float4 xv = xr4[tid * 2 + c];
    float4 ww = wr4[tid * 2 + c];
    sxw += xv.x * ww.x + xv.y * ww.y + xv.z * ww.z + xv.w * ww.w;
    sw  += ww.x + ww.y + ww.z + ww.w;
    int b = 8 * tid + 4 * c;
    key[4*c+0] = ((u64)__float_as_uint(xv.x) << 32) | (unsigned)(b + 0);
    key[4*c+1] = ((u64)__float_as_uint(xv.y) << 32) | (unsigned)(b + 1);
    key[4*c+2] = ((u64)__float_as_uint(xv.z) << 32) | (unsigned)(b + 2);
    key[4*c+3] = ((u64)__float_as_uint(xv.w) << 32) | (unsigned)(b + 3);
  }
#pragma unroll
  for (int off = 32; off > 0; off >>= 1) {
    sxw += __shfl_down(sxw, off);
    sw  += __shfl_down(sw, off);
  }
  if (lane == 0) { redA[wave] = sxw; redB[wave] = sw; }
  __syncthreads();   // [1] zeroed cnt + redA/redB visible

  // ---- histogram on packed u16 fields; pack (bucket, ord) into one word ----
  u32 bo[EPT];
#pragma unroll
  for (int e = 0; e < EPT; ++e) {
    int b = bucket_of_bits((unsigned)(key[e] >> 32));
    u32 inc = (b & 1) ? 65536u : 1u;
    u32 ret = atomicAdd(&cntw[b >> 1], inc);
    u32 o = (b & 1) ? (ret >> 16) : (ret & 0xffffu);
    bo[e] = ((u32)b << 16) | (o & 0xffffu);
  }
  __syncthreads();   // [2] all atomics done
  if (tid == 0) {
    float a = 0.f, b = 0.f;
#pragma unroll
    for (int i = 0; i < NW; ++i) { a += redA[i]; b += redB[i]; }
    s_alpha = a / b - 0.5f;
  }

  // ---- exclusive scan of 2048 u16 counts -> bases (packed, in place) ----
  u32 cv0 = cntw[2 * tid], cv1 = cntw[2 * tid + 1];
  int c0 = (int)(cv0 & 0xffffu), c1 = (int)(cv0 >> 16);
  int c2 = (int)(cv1 & 0xffffu), c3 = (int)(cv1 >> 16);
  int runi = c0 + c1 + c2 + c3;
  int toti = runi, prei = runi;
#pragma unroll
  for (int off = 1; off < 64; off <<= 1) {
    int v = __shfl_up(prei, off);
    if (lane >= off) prei += v;
  }
  if (lane == 63) iwt[wave] = prei;
  __syncthreads();   // [3] iwt visible (each thread only rewrites its own words)
  int wpre = 0;
#pragma unroll
  for (int w2 = 0; w2 < NW; ++w2) wpre += (w2 < wave) ? iwt[w2] : 0;
  int acc = wpre + prei - toti;
  {
    int b0 = acc; acc += c0;
    int b1 = acc; acc += c1;
    int b2 = acc; acc += c2;
    int b3 = acc; acc += c3;
    cntw[2 * tid]     = (u32)b0 | ((u32)b1 << 16);
    cntw[2 * tid + 1] = (u32)b2 | ((u32)b3 << 16);
  }
  if (tid == T - 1) cnt16[NB] = (u16)acc;   // sentinel = 4096
  __syncthreads();   // [4] bases visible

  // ---- scatter keys into bucket slots (arrival order) ----
#pragma unroll
  for (int e = 0; e < EPT; ++e) {
    int b = (int)(bo[e] >> 16);
    int o = (int)(bo[e] & 0xffffu);
    pairs[(int)cnt16[b] + o] = key[e];
  }
  __syncthreads();   // [5]

  // ---- per-bucket sort: branchless in-register sort-4 network + rare tail.
  //      Unique u64 keys -> slot placement is algorithm-independent (bit-exact).
#pragma unroll
  for (int bb = 0; bb < 4; ++bb) {
    int b  = 4 * tid + bb;
    int lo = (int)cnt16[b], hi = (int)cnt16[b + 1];
    int n = hi - lo;
    if (n >= 2) {
      int hm1 = hi - 1;
      u64 e0 = pairs[lo];
      u64 e1 = pairs[lo + 1];
      u64 t2 = pairs[lo + 2 < hm1 ? lo + 2 : hm1];
      u64 t3 = pairs[lo + 3 < hm1 ? lo + 3 : hm1];
      u64 e2 = (n > 2) ? t2 : ~0ull;
      u64 e3 = (n > 3) ? t3 : ~0ull;
      // 5-CE network: (0,1)(2,3)(0,2)(1,3)(1,2)
      { u64 a = e0 < e1 ? e0 : e1; e1 = e0 < e1 ? e1 : e0; e0 = a; }
      { u64 a = e2 < e3 ? e2 : e3; e3 = e2 < e3 ? e3 : e2; e2 = a; }
      { u64 a = e0 < e2 ? e0 : e2; e2 = e0 < e2 ? e2 : e0; e0 = a; }
      { u64 a = e1 < e3 ? e1 : e3; e3 = e1 < e3 ? e3 : e1; e1 = a; }
      { u64 a = e1 < e2 ? e1 : e2; e2 = e1 < e2 ? e2 : e1; e1 = a; }
      pairs[lo]     = e0;
      pairs[lo + 1] = e1;
      if (n > 2) pairs[lo + 2] = e2;
      if (n > 3) pairs[lo + 3] = e3;
      // rare tail (P(n>4) ~ 5%): insert remaining into sorted prefix
      for (int i2 = lo + 4; i2 < hi; ++i2) {
        u64 v = pairs[i2];
        int j = i2 - 1;
        while (j >= lo && pairs[j] > v) { pairs[j + 1] = pairs[j]; --j; }
        pairs[j + 1] = v;
      }
    }
  }
  __syncthreads();   // [6] pairs fully sorted

  // ---- read own 8 sorted slots to registers; gather w; cumsum in regs ----
  u64 q[EPT];
  {
    const ulonglong2* pr2 = (const ulonglong2*)pairs + 4 * tid;
#pragma unroll
    for (int c = 0; c < 4; ++c) { ulonglong2 v = pr2[c]; q[2*c] = v.x; q[2*c+1] = v.y; }
  }
  float wg[EPT];
#pragma unroll
  for (int e = 0; e < EPT; ++e) wg[e] = wr[(u32)(q[e] & 0xffffffffu)];
  float lw[EPT];
  float runf = 0.f;
#pragma unroll
  for (int c = 0; c < EPT; ++c) { runf += wg[c]; lw[c] = runf; }
  float totf = runf, pref = runf;
#pragma unroll
  for (int off = 1; off < 64; off <<= 1) {
    float v = __shfl_up(pref, off);
    if (lane >= off) pref += v;
  }
  if (lane == 63) fwt[wave] = pref;
  __syncthreads();   // [7] fwt visible; ALL pairs reads complete
  float wpf = 0.f;
#pragma unroll
  for (int w2 = 0; w2 < NW; ++w2) wpf += (w2 < wave) ? fwt[w2] : 0.f;
  float basef = wpf + pref - totf;
  float xv[EPT], yv[EPT];
#pragma unroll
  for (int c = 0; c < EPT; ++c) {
    xv[c] = __uint_as_float((u32)(q[c] >> 32));
    yv[c] = basef + lw[c];
  }
  if (lane == 0) { xw8[wave] = xv[0]; yw8[wave] = yv[0]; }
  __syncthreads();   // [8] xw8/yw8 visible; pairs DEAD -> ecdf overlay legal

  // boundary (x,y) of slot 8t+8 = thread t+1's slot 0
  float xb  = __shfl_down(xv[0], 1);
  float ybv = __shfl_down(yv[0], 1);
  if (lane == 63 && wave < NW - 1) { xb = xw8[wave + 1]; ybv = yw8[wave + 1]; }

  // ---- stage 1 INVERTED: direct scatter of ecdf. Thread owns segments
  //      8t..8t+7 (x,y in regs). Grid points per segment form a contiguous
  //      j-range per branch (rest_j strictly increasing); ranges found by
  //      pure-VALU F_edge with exact fp fix-up -> assignment == searchsorted
  //      bit-exactly; ev uses the identical interpolation expression. ----
  for (int b = 0; b < 3; ++b) {
    const int js = 1024 * b;
    const int je = (b == 2) ? 3071 : 1024 * (b + 1);   // j=3071 has floor=2: special
    const float ixbf = (float)(b - 1);
    const float bf = (float)b;
    int Fprev = (tid == 0) ? js : F_edge(xv[0], js, je, ixbf, bf);
#pragma unroll
    for (int c = 0; c < EPT; ++c) {
      int seg = 8 * tid + c;
      if (seg > 4094) break;                           // t=511, c=7: no segment
      int Fnext;
      if (seg == 4094) Fnext = je;
      else Fnext = F_edge((c < 7) ? xv[c + 1] : xb, js, je, ixbf, bf);
      if (Fnext > Fprev) {
        float xc = xv[c], yc = yv[c];
        float x1 = (c < 7) ? xv[c + 1] : xb;
        float y1 = (c < 7) ? yv[c + 1] : ybv;
        float slope = (y1 - yc) * __builtin_amdgcn_rcpf(FEPS + (x1 - xc));
        for (int j = Fprev; j < Fnext; ++j) {
          float rj = rest_at(j, ixbf);
          ecdf[j] = ixbf + (yc + slope * (rj - xc));
        }
      }
      Fprev = Fnext;
    }
  }
  if (tid == 0) {   // j=3071: xnew=2.0 exactly, floor=2, rest=0 -> segment 0
    float slope = (yv[1] - yv[0]) * __builtin_amdgcn_rcpf(FEPS + (xv[1] - xv[0]));
    ecdf[3071] = 2.0f + (yv[0] + slope * (0.0f - xv[0]));
  }
  __syncthreads();   // [9] ecdf complete

  // ---- stage-2 value LUT over ecdf range [-1,2): 257 brackets (proven exact:
  //      bracket search below widens +-1, identical to rounds 0-2) ----
  if (tid < 257) {
    float v = -1.0f + 3.0f * (float)tid * (1.0f / 256.0f);
    lut2[tid] = (u16)lower_bound_f(ecdf, 0, N3, v);
  }
  __syncthreads();   // [10]

  // ---- stage 2: inverse-CDF embedding + circular cost partial sum.
  //      Bracketed searches (lut2), 2 queries fused for probe ILP. ----
  float alpha = s_alpha;
  float accf = 0.f;
  {
    float xg0 = (float)tid / 1024.0f;
    float xg1 = (float)(tid + T) / 1024.0f;
    float q0 = xg0 - alpha;
    float q1 = xg1 - alpha;
    int k20 = (int)floorf((q0 + 1.0f) * (256.0f / 3.0f));
    int k21 = (int)floorf((q1 + 1.0f) * (256.0f / 3.0f));
    k20 = k20 < 0 ? 0 : (k20 > 255 ? 255 : k20);
    k21 = k21 < 0 ? 0 : (k21 > 255 ? 255 : k21);
    int lo0 = (int)lut2[k20 > 0 ? k20 - 1 : 0];
    int hi0 = (int)lut2[k20 < 254 ? k20 + 2 : 256];
    int lo1 = (int)lut2[k21 > 0 ? k21 - 1 : 0];
    int hi1 = (int)lut2[k21 < 254 ? k21 + 2 : 256];
    while ((lo0 < hi0) | (lo1 < hi1)) {
      if (lo0 < hi0) { int m = (lo0 + hi0) >> 1; if (ecdf[m] < q0) lo0 = m + 1; else hi0 = m; }
      if (lo1 < hi1) { int m = (lo1 + hi1) >> 1; if (ecdf[m] < q1) lo1 = m + 1; else hi1 = m; }
    }
    // s = 0 then s = 1: same accumulation order as before
#pragma unroll
    for (int s = 0; s < 2; ++s) {
      int lo = (s == 0) ? lo0 : lo1;
      float q2 = (s == 0) ? q0 : q1;
      float xg = (s == 0) ? xg0 : xg1;
      int ind = lo - 1;
      ind = ind < 0 ? 0 : (ind > N3 - 2 ? N3 - 2 : ind);
      float e0 = ecdf[ind], e1 = ecdf[ind + 1];
      float y0 = -1.0f + (3.0f * (float)ind) / 3071.0f;
      float y1 = -1.0f + (3.0f * (float)(ind + 1)) / 3071.0f;
      float slope = (y1 - y0) * __builtin_amdgcn_rcpf(FEPS + (e1 - e0));
      float emb = y0 + slope * (q2 - e0) - xg;
      float a = fabsf(emb);
      float m = fminf(a, 1.0f - a);
      accf += m * m;
    }
  }
#pragma unroll
  for (int off = 32; off > 0; off >>= 1) accf += __shfl_down(accf, off);
  if (lane == 0) redA[wave] = accf;
  __syncthreads();   // [11]
  if (tid == 0) {
    float s = 0.f;
#pragma unroll
    for (int i = 0; i < NW; ++i) s += redA[i];
    rowsum[row] = s;
  }
}

__global__ __launch_bounds__(256) void lcot_final(const float* __restrict__ rowsum,
                                                  float* __restrict__ out) {
  __shared__ float red[4];
  int t = threadIdx.x;
  float s = 0.f;
  for (int i = t; i < L; i += 256) s += rowsum[i];
#pragma unroll
  for (int off = 32; off > 0; off >>= 1) s += __shfl_down(s, off);
  if ((t & 63) == 0) red[t >> 6] = s;
  __syncthreads();
  if (t == 0) {
    float tot = red[0] + red[1] + red[2] + red[3];
    out[0] = sqrtf(tot / (float)L + 1e-8f);
  }
}

extern "C" void kernel_launch(void* const* d_in, const int* in_sizes, int n_in,
                              void* d_out, int out_size, void* d_ws, size_t ws_size,
                              hipStream_t stream) {
  const float* X = (const float*)d_in[0];
  const float* W = (const float*)d_in[1];
  float* rowsum = (float*)d_ws;  // 2048 floats
  // 32768 (pairs, ecdf overlays) + 4104 (u16 cnt) + 520 (lut2) = 37,392 B
  size_t shbytes = 32768 + 4104 + 520;
  hipLaunchKernelGGL(lcot_rows, dim3(L), dim3(T), shbytes, stream, X, W, rowsum);
  hipLaunchKernelGGL(lcot_final, dim3(1), dim3(256), 0, stream,
                     (const float*)rowsum, (float*)d_out);
}

// Round 8
// 177.003 us; speedup vs baseline: 13.2151x; 13.2151x over previous
//
#include <hip/hip_runtime.h>
#include <math.h>

#define L    2048
#define NCOL 4096
#define NG   1024
#define N3   3072
#define T    512
#define NW   8            // waves per block
#define EPT  8            // NCOL / T
#define NB   2048         // buckets (exact: floor(x*2048), power-of-two mult)
#define FEPS 1.1920929e-07f

typedef unsigned long long u64;
typedef unsigned short u16;
typedef unsigned int u32;

__device__ __forceinline__ int lower_bound_f(const float* a, int lo, int hi, float v) {
  // exact replica of numpy's npy_binsearch (side='left') on [lo,hi)
  while (lo < hi) {
    int mid = (lo + hi) >> 1;
    if (a[mid] < v) lo = mid + 1; else hi = mid;
  }
  return lo;
}

__device__ __forceinline__ int bucket_of_bits(unsigned xb) {
  float f = __uint_as_float(xb);
  int b = (int)(f * (float)NB);          // exact: mult by 2^11
  return b > NB - 1 ? NB - 1 : b;
}

// XOR swizzle for the w/y plane. Blocked access wy[swz(8t+c)] at fixed c:
// each bank hit exactly 2x per 64 lanes (2-way = free). Bijective.
__device__ __forceinline__ int swz(int i) { return i ^ ((i >> 5) & 7); }

// LDS layout (36,872 B dynamic -> 4 blocks/CU, 32 waves/CU):
//   [0,32768)      pairs u64[4096]; aliased later: xs f32[4096] @0,
//                  wy f32[4096] @16384 (sorted w, then in-place CDF ys, swizzled)
//   [16384,28672)  ecdf f32[3072] overlays wy AFTER stage-1 (wy dead by then)
//   [32768,36872)  cnt u16[2050] (packed u32 words for atomics), padded
__global__ __launch_bounds__(T, 8) void lcot_rows(const float* __restrict__ X,
                                                  const float* __restrict__ W,
                                                  float* __restrict__ rowsum,
                                                  u32* __restrict__ done_cnt,
                                                  float* __restrict__ out) {
  extern __shared__ char smem[];
  u64*   pairs = (u64*)smem;
  float* xs    = (float*)smem;
  float* wy    = (float*)(smem + 16384);
  float* ecdf  = (float*)(smem + 16384);          // overlay, used after stage-1
  u16*   cnt16 = (u16*)(smem + 32768);
  u32*   cntw  = (u32*)(smem + 32768);

  __shared__ float redA[NW], redB[NW], fwt[NW];
  __shared__ int   iwt[NW];
  __shared__ float s_alpha;
  __shared__ int   s_last;

  const int tid  = threadIdx.x;
  const int lane = tid & 63;
  const int wave = tid >> 6;
  const int row  = blockIdx.x;
  const float* xr = X + (size_t)row * NCOL;
  const float* wr = W + (size_t)row * NCOL;

  // ---- zero packed histogram (1025 u32 words incl. sentinel word) ----
  for (int i = tid; i < 1025; i += T) cntw[i] = 0u;

  // ---- load 8 consecutive elems, pack stable keys, alpha partials ----
  u64 key[EPT];
  float sxw = 0.f, sw = 0.f;
  const float4* xr4 = (const float4*)xr;
  const float4* wr4 = (const float4*)wr;
#pragma unroll
  for (int c = 0; c < 2; ++c) {
    float4 xv = xr4[tid * 2 + c];
    float4 ww = wr4[tid * 2 + c];
    sxw += xv.x * ww.x + xv.y * ww.y + xv.z * ww.z + xv.w * ww.w;
    sw  += ww.x + ww.y + ww.z + ww.w;
    int b = 8 * tid + 4 * c;
    key[4*c+0] = ((u64)__float_as_uint(xv.x) << 32) | (unsigned)(b + 0);
    key[4*c+1] = ((u64)__float_as_uint(xv.y) << 32) | (unsigned)(b + 1);
    key[4*c+2] = ((u64)__float_as_uint(xv.z) << 32) | (unsigned)(b + 2);
    key[4*c+3] = ((u64)__float_as_uint(xv.w) << 32) | (unsigned)(b + 3);
  }
#pragma unroll
  for (int off = 32; off > 0; off >>= 1) {
    sxw += __shfl_down(sxw, off);
    sw  += __shfl_down(sw, off);
  }
  if (lane == 0) { redA[wave] = sxw; redB[wave] = sw; }
  __syncthreads();   // [1] zeroed cnt + redA/redB visible

  // ---- histogram on packed u16 fields; pack (bucket, ord) into one word ----
  u32 bo[EPT];
#pragma unroll
  for (int e = 0; e < EPT; ++e) {
    int b = bucket_of_bits((unsigned)(key[e] >> 32));
    u32 inc = (b & 1) ? 65536u : 1u;
    u32 ret = atomicAdd(&cntw[b >> 1], inc);
    u32 o = (b & 1) ? (ret >> 16) : (ret & 0xffffu);
    bo[e] = ((u32)b << 16) | (o & 0xffffu);
  }
  __syncthreads();   // [2] all atomics done
  if (tid == 0) {
    float a = 0.f, b = 0.f;
#pragma unroll
    for (int i = 0; i < NW; ++i) { a += redA[i]; b += redB[i]; }
    s_alpha = a / b - 0.5f;
  }

  // ---- exclusive scan of 2048 u16 counts -> bases (packed, in place) ----
  u32 cv0 = cntw[2 * tid], cv1 = cntw[2 * tid + 1];
  int c0 = (int)(cv0 & 0xffffu), c1 = (int)(cv0 >> 16);
  int c2 = (int)(cv1 & 0xffffu), c3 = (int)(cv1 >> 16);
  int runi = c0 + c1 + c2 + c3;
  int toti = runi, prei = runi;
#pragma unroll
  for (int off = 1; off < 64; off <<= 1) {
    int v = __shfl_up(prei, off);
    if (lane >= off) prei += v;
  }
  if (lane == 63) iwt[wave] = prei;
  __syncthreads();   // [3] iwt visible (each thread only rewrites its own words)
  int wpre = 0;
#pragma unroll
  for (int w2 = 0; w2 < NW; ++w2) wpre += (w2 < wave) ? iwt[w2] : 0;
  int acc = wpre + prei - toti;
  {
    int b0 = acc; acc += c0;
    int b1 = acc; acc += c1;
    int b2 = acc; acc += c2;
    int b3 = acc; acc += c3;
    cntw[2 * tid]     = (u32)b0 | ((u32)b1 << 16);
    cntw[2 * tid + 1] = (u32)b2 | ((u32)b3 << 16);
  }
  if (tid == T - 1) cnt16[NB] = (u16)acc;   // sentinel = 4096
  __syncthreads();   // [4] bases visible

  // ---- scatter keys into bucket slots (arrival order) ----
#pragma unroll
  for (int e = 0; e < EPT; ++e) {
    int b = (int)(bo[e] >> 16);
    int o = (int)(bo[e] & 0xffffu);
    pairs[(int)cnt16[b] + o] = key[e];
  }
  __syncthreads();   // [5]

  // ---- per-bucket sort: branchless in-register sort-4 network + rare tail.
  //      Unique u64 keys -> slot placement is algorithm-independent (bit-exact).
#pragma unroll
  for (int bb = 0; bb < 4; ++bb) {
    int b  = 4 * tid + bb;
    int lo = (int)cnt16[b], hi = (int)cnt16[b + 1];
    int n = hi - lo;
    if (n >= 2) {
      int hm1 = hi - 1;
      u64 e0 = pairs[lo];
      u64 e1 = pairs[lo + 1];
      u64 t2 = pairs[lo + 2 < hm1 ? lo + 2 : hm1];
      u64 t3 = pairs[lo + 3 < hm1 ? lo + 3 : hm1];
      u64 e2 = (n > 2) ? t2 : ~0ull;
      u64 e3 = (n > 3) ? t3 : ~0ull;
      // 5-CE network: (0,1)(2,3)(0,2)(1,3)(1,2)
      { u64 a = e0 < e1 ? e0 : e1; e1 = e0 < e1 ? e1 : e0; e0 = a; }
      { u64 a = e2 < e3 ? e2 : e3; e3 = e2 < e3 ? e3 : e2; e2 = a; }
      { u64 a = e0 < e2 ? e0 : e2; e2 = e0 < e2 ? e2 : e0; e0 = a; }
      { u64 a = e1 < e3 ? e1 : e3; e3 = e1 < e3 ? e3 : e1; e1 = a; }
      { u64 a = e1 < e2 ? e1 : e2; e2 = e1 < e2 ? e2 : e1; e1 = a; }
      pairs[lo]     = e0;
      pairs[lo + 1] = e1;
      if (n > 2) pairs[lo + 2] = e2;
      if (n > 3) pairs[lo + 3] = e3;
      // rare tail (P(n>4) ~ 5%): insert remaining into sorted prefix
      for (int i2 = lo + 4; i2 < hi; ++i2) {
        u64 v = pairs[i2];
        int j = i2 - 1;
        while (j >= lo && pairs[j] > v) { pairs[j + 1] = pairs[j]; --j; }
        pairs[j + 1] = v;
      }
    }
  }
  __syncthreads();   // [6] pairs fully sorted

  // ---- finish pass, cyclic ownership (j = tid + 512m): conflict-free ----
  u64 q[EPT];
#pragma unroll
  for (int m = 0; m < EPT; ++m) q[m] = pairs[tid + m * T];
  float wg[EPT];
#pragma unroll
  for (int m = 0; m < EPT; ++m) wg[m] = wr[(u32)(q[m] & 0xffffffffu)];
  __syncthreads();   // [7] all pairs reads done before aliasing xs/wy writes

#pragma unroll
  for (int m = 0; m < EPT; ++m) {
    int j = tid + m * T;
    xs[j]      = __uint_as_float((u32)(q[m] >> 32));   // bank t%32: free
    wy[swz(j)] = wg[m];                                 // ~2-way: free
  }
  __syncthreads();   // [8] sorted xs + w visible

  // ---- cumsum weights (blocked read of own 8 sorted slots, swizzled=free;
  //      identical per-thread summation order as before) ----
  float lw[EPT];
  float runf = 0.f;
#pragma unroll
  for (int c = 0; c < EPT; ++c) {
    runf += wy[swz(8 * tid + c)];
    lw[c] = runf;
  }
  float totf = runf, pref = runf;
#pragma unroll
  for (int off = 1; off < 64; off <<= 1) {
    float v = __shfl_up(pref, off);
    if (lane >= off) pref += v;
  }
  if (lane == 63) fwt[wave] = pref;
  __syncthreads();   // [9] fwt visible
  float wpf = 0.f;
#pragma unroll
  for (int w2 = 0; w2 < NW; ++w2) wpf += (w2 < wave) ? fwt[w2] : 0.f;
  float basef = wpf + pref - totf;
#pragma unroll
  for (int c = 0; c < EPT; ++c) wy[swz(8 * tid + c)] = basef + lw[c];
  __syncthreads();   // [10] xs + CDF visible

  // ---- stage 1: ecdf values into REGISTERS.
  //      6 independent searches fused in 2 groups of 3: one while-loop steps
  //      all active searches -> LDS latencies overlap, chain = max(trips)
  //      not sum(trips). Each search keeps the exact npy midpoint sequence. ----
  float ev[N3 / T];
#pragma unroll
  for (int g = 0; g < 2; ++g) {
    int lo0, hi0, lo1, hi1, lo2, hi2;
    float r0, r1, r2;
    {
      int j = tid + (3 * g + 0) * T;
      float xnew = -1.0f + (3.0f * (float)j) / 3071.0f;
      r0 = xnew - floorf(xnew);
      int k = (int)(r0 * (float)NB); k = k > NB - 1 ? NB - 1 : k;
      lo0 = (int)cnt16[k]; hi0 = (int)cnt16[k + 1];
    }
    {
      int j = tid + (3 * g + 1) * T;
      float xnew = -1.0f + (3.0f * (float)j) / 3071.0f;
      r1 = xnew - floorf(xnew);
      int k = (int)(r1 * (float)NB); k = k > NB - 1 ? NB - 1 : k;
      lo1 = (int)cnt16[k]; hi1 = (int)cnt16[k + 1];
    }
    {
      int j = tid + (3 * g + 2) * T;
      float xnew = -1.0f + (3.0f * (float)j) / 3071.0f;
      r2 = xnew - floorf(xnew);
      int k = (int)(r2 * (float)NB); k = k > NB - 1 ? NB - 1 : k;
      lo2 = (int)cnt16[k]; hi2 = (int)cnt16[k + 1];
    }
    while ((lo0 < hi0) | (lo1 < hi1) | (lo2 < hi2)) {
      if (lo0 < hi0) { int m = (lo0 + hi0) >> 1; if (xs[m] < r0) lo0 = m + 1; else hi0 = m; }
      if (lo1 < hi1) { int m = (lo1 + hi1) >> 1; if (xs[m] < r1) lo1 = m + 1; else hi1 = m; }
      if (lo2 < hi2) { int m = (lo2 + hi2) >> 1; if (xs[m] < r2) lo2 = m + 1; else hi2 = m; }
    }
    // interpolation: 3 independent load groups, ILP'd
#pragma unroll
    for (int s3 = 0; s3 < 3; ++s3) {
      int s = 3 * g + s3;
      int lb = (s3 == 0) ? lo0 : (s3 == 1) ? lo1 : lo2;
      float rest = (s3 == 0) ? r0 : (s3 == 1) ? r1 : r2;
      int j = tid + s * T;
      float xnew = -1.0f + (3.0f * (float)j) / 3071.0f;
      float ix = floorf(xnew);
      int ind = lb - 1;
      ind = ind < 0 ? 0 : (ind > NCOL - 2 ? NCOL - 2 : ind);
      float x0 = xs[ind], x1v = xs[ind + 1];
      float y0 = wy[swz(ind)], y1v = wy[swz(ind + 1)];
      float slope = (y1v - y0) * __builtin_amdgcn_rcpf(FEPS + (x1v - x0));
      ev[s] = ix + (y0 + slope * (rest - x0));
    }
  }
  __syncthreads();   // [11] all xs/wy reads done -> wy region reusable

  // ---- write ecdf overlay (over dead wy region) ----
#pragma unroll
  for (int s = 0; s < N3 / T; ++s) ecdf[tid + s * T] = ev[s];
  __syncthreads();   // [12]

  // ---- stage 2: inverse-CDF embedding + circular cost partial sum.
  //      Exact FULL-range lower_bound (= the reference's searchsorted).
  //      Both queries fused: identical [0,3072) start -> trip count ~12 for
  //      every lane, near-zero divergence, 2-way ILP on the probe reads. ----
  float alpha = s_alpha;
  float accf = 0.f;
  {
    float xg0 = (float)tid / 1024.0f;
    float xg1 = (float)(tid + T) / 1024.0f;
    float q0 = xg0 - alpha;
    float q1 = xg1 - alpha;
    int lo0 = 0, hi0 = N3, lo1 = 0, hi1 = N3;
    while ((lo0 < hi0) | (lo1 < hi1)) {
      if (lo0 < hi0) { int m = (lo0 + hi0) >> 1; if (ecdf[m] < q0) lo0 = m + 1; else hi0 = m; }
      if (lo1 < hi1) { int m = (lo1 + hi1) >> 1; if (ecdf[m] < q1) lo1 = m + 1; else hi1 = m; }
    }
    // s = 0 then s = 1: same accumulation order as before
#pragma unroll
    for (int s = 0; s < 2; ++s) {
      int lo = (s == 0) ? lo0 : lo1;
      float q2 = (s == 0) ? q0 : q1;
      float xg = (s == 0) ? xg0 : xg1;
      int ind = lo - 1;
      ind = ind < 0 ? 0 : (ind > N3 - 2 ? N3 - 2 : ind);
      float e0 = ecdf[ind], e1 = ecdf[ind + 1];
      float y0 = -1.0f + (3.0f * (float)ind) / 3071.0f;
      float y1 = -1.0f + (3.0f * (float)(ind + 1)) / 3071.0f;
      float slope = (y1 - y0) * __builtin_amdgcn_rcpf(FEPS + (e1 - e0));
      float emb = y0 + slope * (q2 - e0) - xg;
      float a = fabsf(emb);
      float m = fminf(a, 1.0f - a);
      accf += m * m;
    }
  }
#pragma unroll
  for (int off = 32; off > 0; off >>= 1) accf += __shfl_down(accf, off);
  if (lane == 0) redA[wave] = accf;
  __syncthreads();   // [13]

  // ---- publish rowsum + last-block-done final reduction (replaces the
  //      lcot_final launch; bit-identical summation order). G16 pattern:
  //      device-scope release store + acq_rel counter + agent atomic loads. ----
  if (tid == 0) {
    float s = 0.f;
#pragma unroll
    for (int i = 0; i < NW; ++i) s += redA[i];
    __hip_atomic_store(&rowsum[row], s, __ATOMIC_RELEASE, __HIP_MEMORY_SCOPE_AGENT);
    u32 old = __hip_atomic_fetch_add(done_cnt, 1u, __ATOMIC_ACQ_REL,
                                     __HIP_MEMORY_SCOPE_AGENT);
    s_last = (old == (u32)(L - 1));
  }
  __syncthreads();   // [14] s_last visible
  if (s_last) {
    // exact replica of lcot_final on the first 256 threads
    float s = 0.f;
    if (tid < 256) {
      for (int i = tid; i < L; i += 256)
        s += __hip_atomic_load(&rowsum[i], __ATOMIC_RELAXED, __HIP_MEMORY_SCOPE_AGENT);
#pragma unroll
      for (int off = 32; off > 0; off >>= 1) s += __shfl_down(s, off);
      if ((tid & 63) == 0) redB[tid >> 6] = s;
    }
    __syncthreads();
    if (tid == 0) {
      float tot = redB[0] + redB[1] + redB[2] + redB[3];
      out[0] = sqrtf(tot / (float)L + 1e-8f);
    }
  }
}

extern "C" void kernel_launch(void* const* d_in, const int* in_sizes, int n_in,
                              void* d_out, int out_size, void* d_ws, size_t ws_size,
                              hipStream_t stream) {
  const float* X = (const float*)d_in[0];
  const float* W = (const float*)d_in[1];
  float* rowsum = (float*)d_ws;                       // 2048 floats
  u32*   done   = (u32*)((char*)d_ws + L * sizeof(float));
  hipMemsetAsync(done, 0, sizeof(u32), stream);       // graph-capturable
  // 32768 (pairs/xs/wy, ecdf overlays wy) + 4104 (u16 cnt) = 36,872 B
  size_t shbytes = 32768 + 4104;
  hipLaunchKernelGGL(lcot_rows, dim3(L), dim3(T), shbytes, stream,
                     X, W, rowsum, done, (float*)d_out);
}

// Round 9
// 174.790 us; speedup vs baseline: 13.3824x; 1.0127x over previous
//
#include <hip/hip_runtime.h>
#include <math.h>

#define L    2048
#define NCOL 4096
#define NG   1024
#define N3   3072
#define T    512
#define NW   8            // waves per block
#define EPT  8            // NCOL / T
#define NB   3072         // buckets; monotone+consistent float bucketing (see note)
#define NBW  1536         // NB/2 packed u32 words
#define FEPS 1.1920929e-07f

typedef unsigned long long u64;
typedef unsigned short u16;
typedef unsigned int u32;

__device__ __forceinline__ int lower_bound_f(const float* a, int lo, int hi, float v) {
  // exact replica of numpy's npy_binsearch (side='left') on [lo,hi)
  while (lo < hi) {
    int mid = (lo + hi) >> 1;
    if (a[mid] < v) lo = mid + 1; else hi = mid;
  }
  return lo;
}

// NOTE on NB=3072 exactness: bucketing is OUR bracket construct, not the
// reference's. Correctness needs only (a) monotone in x, (b) the IDENTICAL
// fp expression for elements and queries. (int)(f*3072.0f) satisfies both
// (mult by positive const is monotone; same expr both sites). max f<1 ->
// f*3072 rounds to <=3071.9998 < 3072; clamp kept anyway.
__device__ __forceinline__ int bucket_of_bits(unsigned xb) {
  float f = __uint_as_float(xb);
  int b = (int)(f * (float)NB);
  return b > NB - 1 ? NB - 1 : b;
}

// XOR swizzle for the w/y plane. Blocked access wy[swz(8t+c)] at fixed c:
// each bank hit exactly 2x per 64 lanes (2-way = free). Bijective.
__device__ __forceinline__ int swz(int i) { return i ^ ((i >> 5) & 7); }

// LDS layout (38,920 B dynamic -> 4 blocks/CU, 32 waves/CU):
//   [0,32768)      pairs u64[4096]; aliased later: xs f32[4096] @0,
//                  wy f32[4096] @16384 (sorted w, then in-place CDF ys, swizzled)
//   [16384,28672)  ecdf f32[3072] overlays wy AFTER stage-1 (wy dead by then)
//   [32768,38920)  cnt u16[3074] (packed u32 words for atomics), padded
__global__ __launch_bounds__(T, 8) void lcot_rows(const float* __restrict__ X,
                                                  const float* __restrict__ W,
                                                  float* __restrict__ rowsum,
                                                  u32* __restrict__ done_cnt,
                                                  float* __restrict__ out) {
  extern __shared__ char smem[];
  u64*   pairs = (u64*)smem;
  float* xs    = (float*)smem;
  float* wy    = (float*)(smem + 16384);
  float* ecdf  = (float*)(smem + 16384);          // overlay, used after stage-1
  u16*   cnt16 = (u16*)(smem + 32768);
  u32*   cntw  = (u32*)(smem + 32768);

  __shared__ float redA[NW], redB[NW], fwt[NW];
  __shared__ int   iwt[NW];
  __shared__ float s_alpha;
  __shared__ int   s_last;

  const int tid  = threadIdx.x;
  const int lane = tid & 63;
  const int wave = tid >> 6;
  const int row  = blockIdx.x;
  const float* xr = X + (size_t)row * NCOL;
  const float* wr = W + (size_t)row * NCOL;

  // ---- zero packed histogram (1537 u32 words incl. sentinel word) ----
  for (int i = tid; i < NBW + 1; i += T) cntw[i] = 0u;

  // ---- load 8 consecutive elems, pack stable keys, alpha partials ----
  u64 key[EPT];
  float sxw = 0.f, sw = 0.f;
  const float4* xr4 = (const float4*)xr;
  const float4* wr4 = (const float4*)wr;
#pragma unroll
  for (int c = 0; c < 2; ++c) {
    float4 xv = xr4[tid * 2 + c];
    float4 ww = wr4[tid * 2 + c];
    sxw += xv.x * ww.x + xv.y * ww.y + xv.z * ww.z + xv.w * ww.w;
    sw  += ww.x + ww.y + ww.z + ww.w;
    int b = 8 * tid + 4 * c;
    key[4*c+0] = ((u64)__float_as_uint(xv.x) << 32) | (unsigned)(b + 0);
    key[4*c+1] = ((u64)__float_as_uint(xv.y) << 32) | (unsigned)(b + 1);
    key[4*c+2] = ((u64)__float_as_uint(xv.z) << 32) | (unsigned)(b + 2);
    key[4*c+3] = ((u64)__float_as_uint(xv.w) << 32) | (unsigned)(b + 3);
  }
#pragma unroll
  for (int off = 32; off > 0; off >>= 1) {
    sxw += __shfl_down(sxw, off);
    sw  += __shfl_down(sw, off);
  }
  if (lane == 0) { redA[wave] = sxw; redB[wave] = sw; }
  __syncthreads();   // [1] zeroed cnt + redA/redB visible

  // ---- histogram on packed u16 fields; pack (bucket, ord) into one word ----
  u32 bo[EPT];
#pragma unroll
  for (int e = 0; e < EPT; ++e) {
    int b = bucket_of_bits((unsigned)(key[e] >> 32));
    u32 inc = (b & 1) ? 65536u : 1u;
    u32 ret = atomicAdd(&cntw[b >> 1], inc);
    u32 o = (b & 1) ? (ret >> 16) : (ret & 0xffffu);
    bo[e] = ((u32)b << 16) | (o & 0xffffu);
  }
  __syncthreads();   // [2] all atomics done
  if (tid == 0) {
    float a = 0.f, b = 0.f;
#pragma unroll
    for (int i = 0; i < NW; ++i) { a += redA[i]; b += redB[i]; }
    s_alpha = a / b - 0.5f;
  }

  // ---- exclusive scan of 3072 u16 counts (6/thread) -> bases, in place ----
  u32 cv0 = cntw[3 * tid], cv1 = cntw[3 * tid + 1], cv2 = cntw[3 * tid + 2];
  int c0 = (int)(cv0 & 0xffffu), c1 = (int)(cv0 >> 16);
  int c2 = (int)(cv1 & 0xffffu), c3 = (int)(cv1 >> 16);
  int c4 = (int)(cv2 & 0xffffu), c5 = (int)(cv2 >> 16);
  int runi = c0 + c1 + c2 + c3 + c4 + c5;
  int toti = runi, prei = runi;
#pragma unroll
  for (int off = 1; off < 64; off <<= 1) {
    int v = __shfl_up(prei, off);
    if (lane >= off) prei += v;
  }
  if (lane == 63) iwt[wave] = prei;
  __syncthreads();   // [3] iwt visible (each thread only rewrites its own words)
  int wpre = 0;
#pragma unroll
  for (int w2 = 0; w2 < NW; ++w2) wpre += (w2 < wave) ? iwt[w2] : 0;
  int acc = wpre + prei - toti;
  {
    int b0 = acc; acc += c0;
    int b1 = acc; acc += c1;
    int b2 = acc; acc += c2;
    int b3 = acc; acc += c3;
    int b4 = acc; acc += c4;
    int b5 = acc; acc += c5;
    cntw[3 * tid]     = (u32)b0 | ((u32)b1 << 16);
    cntw[3 * tid + 1] = (u32)b2 | ((u32)b3 << 16);
    cntw[3 * tid + 2] = (u32)b4 | ((u32)b5 << 16);
  }
  if (tid == T - 1) cnt16[NB] = (u16)acc;   // sentinel = 4096 (word NBW, own slot)
  __syncthreads();   // [4] bases visible

  // ---- scatter keys into bucket slots (arrival order) ----
#pragma unroll
  for (int e = 0; e < EPT; ++e) {
    int b = (int)(bo[e] >> 16);
    int o = (int)(bo[e] & 0xffffu);
    pairs[(int)cnt16[b] + o] = key[e];
  }
  __syncthreads();   // [5]

  // ---- per-bucket sort (6 buckets/thread, lambda=1.33): branchless sort-4
  //      network + rare tail. Unique u64 keys -> placement is algorithm-
  //      independent (bit-exact vs insertion sort). ----
#pragma unroll
  for (int bb = 0; bb < 6; ++bb) {
    int b  = 6 * tid + bb;
    int lo = (int)cnt16[b], hi = (int)cnt16[b + 1];
    int n = hi - lo;
    if (n >= 2) {
      int hm1 = hi - 1;
      u64 e0 = pairs[lo];
      u64 e1 = pairs[lo + 1];
      u64 t2 = pairs[lo + 2 < hm1 ? lo + 2 : hm1];
      u64 t3 = pairs[lo + 3 < hm1 ? lo + 3 : hm1];
      u64 e2 = (n > 2) ? t2 : ~0ull;
      u64 e3 = (n > 3) ? t3 : ~0ull;
      // 5-CE network: (0,1)(2,3)(0,2)(1,3)(1,2)
      { u64 a = e0 < e1 ? e0 : e1; e1 = e0 < e1 ? e1 : e0; e0 = a; }
      { u64 a = e2 < e3 ? e2 : e3; e3 = e2 < e3 ? e3 : e2; e2 = a; }
      { u64 a = e0 < e2 ? e0 : e2; e2 = e0 < e2 ? e2 : e0; e0 = a; }
      { u64 a = e1 < e3 ? e1 : e3; e3 = e1 < e3 ? e3 : e1; e1 = a; }
      { u64 a = e1 < e2 ? e1 : e2; e2 = e1 < e2 ? e2 : e1; e1 = a; }
      pairs[lo]     = e0;
      pairs[lo + 1] = e1;
      if (n > 2) pairs[lo + 2] = e2;
      if (n > 3) pairs[lo + 3] = e3;
      // rare tail (P(n>4|lambda=1.33) ~ 1%): insert into sorted prefix
      for (int i2 = lo + 4; i2 < hi; ++i2) {
        u64 v = pairs[i2];
        int j = i2 - 1;
        while (j >= lo && pairs[j] > v) { pairs[j + 1] = pairs[j]; --j; }
        pairs[j + 1] = v;
      }
    }
  }
  __syncthreads();   // [6] pairs fully sorted

  // ---- finish pass, cyclic ownership (j = tid + 512m): conflict-free ----
  u64 q[EPT];
#pragma unroll
  for (int m = 0; m < EPT; ++m) q[m] = pairs[tid + m * T];
  float wg[EPT];
#pragma unroll
  for (int m = 0; m < EPT; ++m) wg[m] = wr[(u32)(q[m] & 0xffffffffu)];
  __syncthreads();   // [7] all pairs reads done before aliasing xs/wy writes

#pragma unroll
  for (int m = 0; m < EPT; ++m) {
    int j = tid + m * T;
    xs[j]      = __uint_as_float((u32)(q[m] >> 32));   // bank t%32: free
    wy[swz(j)] = wg[m];                                 // ~2-way: free
  }
  __syncthreads();   // [8] sorted xs + w visible

  // ---- cumsum weights (blocked read of own 8 sorted slots, swizzled=free;
  //      identical per-thread summation order as before) ----
  float lw[EPT];
  float runf = 0.f;
#pragma unroll
  for (int c = 0; c < EPT; ++c) {
    runf += wy[swz(8 * tid + c)];
    lw[c] = runf;
  }
  float totf = runf, pref = runf;
#pragma unroll
  for (int off = 1; off < 64; off <<= 1) {
    float v = __shfl_up(pref, off);
    if (lane >= off) pref += v;
  }
  if (lane == 63) fwt[wave] = pref;
  __syncthreads();   // [9] fwt visible
  float wpf = 0.f;
#pragma unroll
  for (int w2 = 0; w2 < NW; ++w2) wpf += (w2 < wave) ? fwt[w2] : 0.f;
  float basef = wpf + pref - totf;
#pragma unroll
  for (int c = 0; c < EPT; ++c) wy[swz(8 * tid + c)] = basef + lw[c];
  __syncthreads();   // [10] xs + CDF visible

  // ---- stage 1: ecdf values into REGISTERS.
  //      6 independent searches fused in 2 groups of 3: one while-loop steps
  //      all active searches -> LDS latencies overlap, chain = max(trips)
  //      not sum(trips). Each search keeps the exact npy midpoint sequence. ----
  float ev[N3 / T];
#pragma unroll
  for (int g = 0; g < 2; ++g) {
    int lo0, hi0, lo1, hi1, lo2, hi2;
    float r0, r1, r2;
    {
      int j = tid + (3 * g + 0) * T;
      float xnew = -1.0f + (3.0f * (float)j) / 3071.0f;
      r0 = xnew - floorf(xnew);
      int k = (int)(r0 * (float)NB); k = k > NB - 1 ? NB - 1 : k;
      lo0 = (int)cnt16[k]; hi0 = (int)cnt16[k + 1];
    }
    {
      int j = tid + (3 * g + 1) * T;
      float xnew = -1.0f + (3.0f * (float)j) / 3071.0f;
      r1 = xnew - floorf(xnew);
      int k = (int)(r1 * (float)NB); k = k > NB - 1 ? NB - 1 : k;
      lo1 = (int)cnt16[k]; hi1 = (int)cnt16[k + 1];
    }
    {
      int j = tid + (3 * g + 2) * T;
      float xnew = -1.0f + (3.0f * (float)j) / 3071.0f;
      r2 = xnew - floorf(xnew);
      int k = (int)(r2 * (float)NB); k = k > NB - 1 ? NB - 1 : k;
      lo2 = (int)cnt16[k]; hi2 = (int)cnt16[k + 1];
    }
    while ((lo0 < hi0) | (lo1 < hi1) | (lo2 < hi2)) {
      if (lo0 < hi0) { int m = (lo0 + hi0) >> 1; if (xs[m] < r0) lo0 = m + 1; else hi0 = m; }
      if (lo1 < hi1) { int m = (lo1 + hi1) >> 1; if (xs[m] < r1) lo1 = m + 1; else hi1 = m; }
      if (lo2 < hi2) { int m = (lo2 + hi2) >> 1; if (xs[m] < r2) lo2 = m + 1; else hi2 = m; }
    }
    // interpolation: 3 independent load groups, ILP'd
#pragma unroll
    for (int s3 = 0; s3 < 3; ++s3) {
      int s = 3 * g + s3;
      int lb = (s3 == 0) ? lo0 : (s3 == 1) ? lo1 : lo2;
      float rest = (s3 == 0) ? r0 : (s3 == 1) ? r1 : r2;
      int j = tid + s * T;
      float xnew = -1.0f + (3.0f * (float)j) / 3071.0f;
      float ix = floorf(xnew);
      int ind = lb - 1;
      ind = ind < 0 ? 0 : (ind > NCOL - 2 ? NCOL - 2 : ind);
      float x0 = xs[ind], x1v = xs[ind + 1];
      float y0 = wy[swz(ind)], y1v = wy[swz(ind + 1)];
      float slope = (y1v - y0) * __builtin_amdgcn_rcpf(FEPS + (x1v - x0));
      ev[s] = ix + (y0 + slope * (rest - x0));
    }
  }
  __syncthreads();   // [11] all xs/wy reads done -> wy region reusable

  // ---- write ecdf overlay (over dead wy region) ----
#pragma unroll
  for (int s = 0; s < N3 / T; ++s) ecdf[tid + s * T] = ev[s];
  __syncthreads();   // [12]

  // ---- stage 2: inverse-CDF embedding + circular cost partial sum.
  //      Exact FULL-range lower_bound (= the reference's searchsorted).
  //      Both queries fused: identical [0,3072) start -> trip count ~12 for
  //      every lane, near-zero divergence, 2-way ILP on the probe reads. ----
  float alpha = s_alpha;
  float accf = 0.f;
  {
    float xg0 = (float)tid / 1024.0f;
    float xg1 = (float)(tid + T) / 1024.0f;
    float q0 = xg0 - alpha;
    float q1 = xg1 - alpha;
    int lo0 = 0, hi0 = N3, lo1 = 0, hi1 = N3;
    while ((lo0 < hi0) | (lo1 < hi1)) {
      if (lo0 < hi0) { int m = (lo0 + hi0) >> 1; if (ecdf[m] < q0) lo0 = m + 1; else hi0 = m; }
      if (lo1 < hi1) { int m = (lo1 + hi1) >> 1; if (ecdf[m] < q1) lo1 = m + 1; else hi1 = m; }
    }
    // s = 0 then s = 1: same accumulation order as before
#pragma unroll
    for (int s = 0; s < 2; ++s) {
      int lo = (s == 0) ? lo0 : lo1;
      float q2 = (s == 0) ? q0 : q1;
      float xg = (s == 0) ? xg0 : xg1;
      int ind = lo - 1;
      ind = ind < 0 ? 0 : (ind > N3 - 2 ? N3 - 2 : ind);
      float e0 = ecdf[ind], e1 = ecdf[ind + 1];
      float y0 = -1.0f + (3.0f * (float)ind) / 3071.0f;
      float y1 = -1.0f + (3.0f * (float)(ind + 1)) / 3071.0f;
      float slope = (y1 - y0) * __builtin_amdgcn_rcpf(FEPS + (e1 - e0));
      float emb = y0 + slope * (q2 - e0) - xg;
      float a = fabsf(emb);
      float m = fminf(a, 1.0f - a);
      accf += m * m;
    }
  }
#pragma unroll
  for (int off = 32; off > 0; off >>= 1) accf += __shfl_down(accf, off);
  if (lane == 0) redA[wave] = accf;
  __syncthreads();   // [13]

  // ---- publish rowsum + last-block-done final reduction (replaces the
  //      lcot_final launch; bit-identical summation order). G16 pattern:
  //      device-scope release store + acq_rel counter + agent atomic loads. ----
  if (tid == 0) {
    float s = 0.f;
#pragma unroll
    for (int i = 0; i < NW; ++i) s += redA[i];
    __hip_atomic_store(&rowsum[row], s, __ATOMIC_RELEASE, __HIP_MEMORY_SCOPE_AGENT);
    u32 old = __hip_atomic_fetch_add(done_cnt, 1u, __ATOMIC_ACQ_REL,
                                     __HIP_MEMORY_SCOPE_AGENT);
    s_last = (old == (u32)(L - 1));
  }
  __syncthreads();   // [14] s_last visible
  if (s_last) {
    // exact replica of lcot_final on the first 256 threads
    float s = 0.f;
    if (tid < 256) {
      for (int i = tid; i < L; i += 256)
        s += __hip_atomic_load(&rowsum[i], __ATOMIC_RELAXED, __HIP_MEMORY_SCOPE_AGENT);
#pragma unroll
      for (int off = 32; off > 0; off >>= 1) s += __shfl_down(s, off);
      if ((tid & 63) == 0) redB[tid >> 6] = s;
    }
    __syncthreads();
    if (tid == 0) {
      float tot = redB[0] + redB[1] + redB[2] + redB[3];
      out[0] = sqrtf(tot / (float)L + 1e-8f);
    }
  }
}

extern "C" void kernel_launch(void* const* d_in, const int* in_sizes, int n_in,
                              void* d_out, int out_size, void* d_ws, size_t ws_size,
                              hipStream_t stream) {
  const float* X = (const float*)d_in[0];
  const float* W = (const float*)d_in[1];
  float* rowsum = (float*)d_ws;                       // 2048 floats
  u32*   done   = (u32*)((char*)d_ws + L * sizeof(float));
  hipMemsetAsync(done, 0, sizeof(u32), stream);       // graph-capturable
  // 32768 (pairs/xs/wy, ecdf overlays wy) + 6152 (u16 cnt, NB=3072) = 38,920 B
  size_t shbytes = 32768 + 6152;
  hipLaunchKernelGGL(lcot_rows, dim3(L), dim3(T), shbytes, stream,
                     X, W, rowsum, done, (float*)d_out);
}